// Round 19
// baseline (341.603 us; speedup 1.0000x reference)
//
#include <hip/hip_runtime.h>
#include <stdint.h>

typedef unsigned short u16;
typedef float f32x4 __attribute__((ext_vector_type(4)));
typedef short bf16x8 __attribute__((ext_vector_type(8)));

// ---------- helpers ----------
static __device__ __forceinline__ u16 f2bf(float f) {
  union { float f; unsigned u; } a; a.f = f;
  unsigned r = a.u + 0x7fffu + ((a.u >> 16) & 1u);   // round-nearest-even
  return (u16)(r >> 16);
}

static __device__ __forceinline__ void gld16(const void* g, void* l) {
  __builtin_amdgcn_global_load_lds(
      (const __attribute__((address_space(1))) void*)(uintptr_t)g,
      (__attribute__((address_space(3))) void*)(uintptr_t)l,
      16, 0, 0);
}

// ================== K1: all input-only work (VERBATIM r15 — proven) ==================
__global__ __launch_bounds__(256, 4) void fused_pre(
    const float* __restrict__ x, const float* __restrict__ Wg,
    const float* __restrict__ Wb, const float* __restrict__ B,
    const float* __restrict__ A,
    u16* __restrict__ Xaug, u16* __restrict__ Waug, u16* __restrict__ a2,
    float* __restrict__ wsc) {
  const int bid = blockIdx.x;
  const int t = threadIdx.x;
  if (bid < 512) {
    const int lane = t & 63;
    const int wv = t >> 6;
    const int n0 = bid * 16 + wv * 4;
    const float4* g4 = (const float4*)Wg;      // [8][1024] float4
    float acc[4][8] = {};
#pragma unroll 2
    for (int ii = 0; ii < 16; ++ii) {
      const int i = ii * 64 + lane;
      float4 xv[4];
#pragma unroll
      for (int tok = 0; tok < 4; ++tok) {
        xv[tok] = *(const float4*)(x + (size_t)(n0 + tok) * 4096 + i * 4);
        ushort4 o;
        o.x = f2bf(xv[tok].x); o.y = f2bf(xv[tok].y);
        o.z = f2bf(xv[tok].z); o.w = f2bf(xv[tok].w);
        *(ushort4*)(Xaug + (size_t)(n0 + tok) * 4224 + i * 4) = o;
      }
#pragma unroll
      for (int e = 0; e < 8; ++e) {
        float4 w4 = g4[e * 1024 + i];
#pragma unroll
        for (int tok = 0; tok < 4; ++tok)
          acc[tok][e] += xv[tok].x * w4.x + xv[tok].y * w4.y +
                         xv[tok].z * w4.z + xv[tok].w * w4.w;
      }
    }
#pragma unroll
    for (int tok = 0; tok < 4; ++tok) {
#pragma unroll
      for (int e = 0; e < 8; ++e) {
#pragma unroll
        for (int off = 32; off > 0; off >>= 1)
          acc[tok][e] += __shfl_xor(acc[tok][e], off);
      }
      int i1 = 0; float m1 = acc[tok][0];
#pragma unroll
      for (int e = 1; e < 8; ++e) if (acc[tok][e] > m1) { m1 = acc[tok][e]; i1 = e; }
      int i2 = -1; float m2 = -3.4e38f;
#pragma unroll
      for (int e = 0; e < 8; ++e)
        if (e != i1 && acc[tok][e] > m2) { m2 = acc[tok][e]; i2 = e; }
      float w1 = 1.0f / (1.0f + expf(m2 - m1));   // p1/(p1+p2) softmax+renorm
      float w2 = 1.0f - w1;
      if (lane < 8)
        wsc[(size_t)(n0 + tok) * 8 + lane] =
            (lane == i1) ? w1 : ((lane == i2) ? w2 : 0.0f);
    }
  } else if (bid < 2560) {
    const int total = 4096 * 1056;               // vec4 groups
    for (int v = (bid - 512) * 256 + t; v < total; v += 2048 * 256) {
      const int o = v / 1056;
      const int c = (v - o * 1056) * 4;
      ushort4 out;
      if (c < 4096) {
        float4 w = *(const float4*)(Wb + (size_t)o * 4096 + c);
        out.x = f2bf(w.x); out.y = f2bf(w.y); out.z = f2bf(w.z); out.w = f2bf(w.w);
      } else {
        const int er = c - 4096;
        const int e = er >> 4;
        const int r = er & 15;
        const float* bp = B + ((size_t)e * 4096 + o) * 16 + r;
        out.x = f2bf(bp[0] * 2.0f); out.y = f2bf(bp[1] * 2.0f);
        out.z = f2bf(bp[2] * 2.0f); out.w = f2bf(bp[3] * 2.0f);
      }
      *(ushort4*)(Waug + (size_t)o * 4224 + c) = out;
    }
  } else {
    const int i = (bid - 2560) * 256 + t;        // 0..131071 vec4 groups
    const size_t e = (size_t)i * 4;
    float4 v = *(const float4*)(A + e);
    ushort4 o;
    o.x = f2bf(v.x); o.y = f2bf(v.y); o.z = f2bf(v.z); o.w = f2bf(v.w);
    *(ushort4*)(a2 + e) = o;
  }
}

// ================== K2: LoRA down-proj + gate-scale (VERBATIM r15, proven) ==================
__global__ __launch_bounds__(256) void lora_hw(
    const u16* __restrict__ Xa, const u16* __restrict__ A2,
    const float* __restrict__ wsc, u16* __restrict__ Xaug) {
  __shared__ __align__(1024) char lds[40960];
  const int t = threadIdx.x;
  const int lane = t & 63;
  const int w = t >> 6;
  const int l15 = lane & 15, lhi = lane >> 4;
  const int brow = blockIdx.x * 32;

  const int sb = (lane << 4) ^ (lane & 32);
  const int srow = sb >> 6;
  const int scol = (sb & 63) >> 1;

  const u16* pA = Xa + (size_t)(brow + (w >> 1) * 16 + srow) * 4224 + (w & 1) * 32 + scol;
  const u16* pB[4];
#pragma unroll
  for (int s = 0; s < 4; ++s) {
    const int idx = w * 4 + s;
    pB[s] = A2 + (size_t)((idx >> 1) * 16 + srow) * 4096 + (idx & 1) * 32 + scol;
  }
  const int dA = w << 10;
  const int dB = 4096 + (w << 12);
  const int innerL = ((l15 << 6) + (lhi << 4)) ^ ((l15 & 8) << 2);

  f32x4 acc[2][2] = {};

  gld16(pA, lds + dA);
#pragma unroll
  for (int s = 0; s < 4; ++s) gld16(pB[s], lds + dB + (s << 10));

  for (int j = 0; j < 64; ++j) {
    const int buf = (j & 1) * 20480;
    const int obuf = buf ^ 20480;
    if (j < 63) {
      const int k1 = (j + 1) * 64;
      gld16(pA + k1, lds + obuf + dA);
#pragma unroll
      for (int s = 0; s < 4; ++s) gld16(pB[s] + k1, lds + obuf + dB + (s << 10));
      asm volatile("s_waitcnt vmcnt(5)" ::: "memory");   // tile j landed
    } else {
      asm volatile("s_waitcnt vmcnt(0)" ::: "memory");
    }
    __syncthreads();
    bf16x8 av[2][2], bv[2][2];
#pragma unroll
    for (int m = 0; m < 2; ++m)
#pragma unroll
      for (int kk = 0; kk < 2; ++kk)
        av[m][kk] = *(const bf16x8*)(lds + buf + ((m * 2 + kk) << 10) + innerL);
#pragma unroll
    for (int n = 0; n < 2; ++n)
#pragma unroll
      for (int kk = 0; kk < 2; ++kk)
        bv[n][kk] = *(const bf16x8*)(lds + buf + 4096 + (((w * 2 + n) * 2 + kk) << 10) + innerL);
#pragma unroll
    for (int kk = 0; kk < 2; ++kk)
#pragma unroll
      for (int m = 0; m < 2; ++m)
#pragma unroll
        for (int n = 0; n < 2; ++n)
          acc[m][n] = __builtin_amdgcn_mfma_f32_16x16x32_bf16(av[m][kk], bv[n][kk], acc[m][n], 0, 0, 0);
    __syncthreads();
  }
#pragma unroll
  for (int m = 0; m < 2; ++m) {
    const int rbase = brow + m * 16 + lhi * 4;
#pragma unroll
    for (int n = 0; n < 2; ++n) {
      const int col = w * 32 + n * 16 + l15;
#pragma unroll
      for (int j = 0; j < 4; ++j) {
        const int row = rbase + j;
        const float g = wsc[(size_t)row * 8 + (col >> 4)];
        Xaug[(size_t)row * 4224 + 4096 + col] = f2bf(acc[m][n][j] * g);
      }
    }
  }
}

// ================== 256x256 main GEMM (r18 schedule; A-stage moved to p3, depth j+2) ==================
// r18 (232us, MfmaUtil 56) with ONE ledger-safe delta: A staged at p3 of tile j as
// A(j+2)->buf.A (was p0 of tile j as A(j+1)->obuf.A).  WAR: buf.A reads (av0
// consumed M0@p0, av1 consumed M2@p2, lgkmcnt-forced before the p2-end BAR) are
// >=1 barrier ahead of the p3-post-BAR write.  vmcnt FIFO at tile j+1 p3:
// B(j+2)[j.p2] + A(j+2)[j.p3] + B(j+3)[j+1.p2] = 12 -> vmcnt(4) retires exactly
// B(j+2)+A(j+2) before their reads, keeps B(j+3).  A slack 3->4 phases, B 5.
// Prologue: A0,B0,A1,B1 staged; vmcnt(8) = steady-state entry invariant.
#define BAR do { asm volatile("" ::: "memory"); __builtin_amdgcn_s_barrier(); asm volatile("" ::: "memory"); } while (0)

#define RDA(BUF, MH)                                                            \
  { _Pragma("unroll") for (int mm = 0; mm < 4; ++mm)                            \
    _Pragma("unroll") for (int kk = 0; kk < 2; ++kk)                            \
      av[mm][kk] = *(const bf16x8*)(lds + (BUF) + fbA + ((((MH) * 4 + mm) * 2 + kk) << 10)); }

#define RDB(BUF, NH)                                                            \
  { _Pragma("unroll") for (int nn = 0; nn < 2; ++nn)                            \
    _Pragma("unroll") for (int kk = 0; kk < 2; ++kk)                            \
      bv[(NH) * 2 + nn][kk] = *(const bf16x8*)(lds + (BUF) + fbB + ((((NH) * 2 + nn) * 2 + kk) << 10)); }

#define MFMAQ(MH, NH)                                                           \
  { __builtin_amdgcn_s_setprio(1);                                              \
    _Pragma("unroll") for (int kk = 0; kk < 2; ++kk)                            \
    _Pragma("unroll") for (int mm = 0; mm < 4; ++mm)                            \
    _Pragma("unroll") for (int nn = 0; nn < 2; ++nn)                            \
      acc[(MH) * 4 + mm][(NH) * 2 + nn] = __builtin_amdgcn_mfma_f32_16x16x32_bf16( \
          av[mm][kk], bv[(NH) * 2 + nn][kk], acc[(MH) * 4 + mm][(NH) * 2 + nn], 0, 0, 0); \
    __builtin_amdgcn_s_setprio(0); }

__global__ __launch_bounds__(512, 2) void gemm8p(
    const u16* __restrict__ Ag, const u16* __restrict__ Bg,
    const float* __restrict__ bias, float* __restrict__ C,
    int lda, int ldb, int ldc, int K) {
  __shared__ __align__(1024) char lds[131072];
  const int t = threadIdx.x;
  const int lane = t & 63;
  const int w = t >> 6;
  const int wr = w >> 2, wc = w & 3;
  const int l15 = lane & 15, lhi = lane >> 4;

  // XCD-slab mapping (verified: FETCH 304->203MB)
  const int bid = blockIdx.x;
  const int g = bid >> 3;
  const int tile_m = (bid & 7) * 4 + (g & 3);
  const int tile_n = g >> 2;
  const int brow = tile_m << 8;
  const int bcol = tile_n << 8;

  // pre-swizzled per-lane source coords (st_16x32 involution)
  const int sb = (lane << 4) ^ (lane & 32);
  const int srow = sb >> 6;
  const int scol = (sb & 63) >> 1;

  const u16* pA[4]; const u16* pB[4];
#pragma unroll
  for (int s = 0; s < 4; ++s) {
    const int idx = w * 4 + s;
    const int rg = idx >> 1, cs = idx & 1;
    pA[s] = Ag + (size_t)(brow + rg * 16 + srow) * lda + cs * 32 + scol;
    pB[s] = Bg + (size_t)(bcol + rg * 16 + srow) * ldb + cs * 32 + scol;
  }
  const int ldsA = w << 12;
  const int ldsB = 32768 + (w << 12);

  const int innerL = ((l15 << 6) + (lhi << 4)) ^ ((l15 & 8) << 2);
  const int fbA = (wr << 14) + innerL;
  const int fbB = 32768 + (wc << 13) + innerL;

  f32x4 acc[8][4] = {};
  bf16x8 av[4][2], bv[4][2];

  const int NT = K >> 6;   // 66 K-tiles

  // ---- prologue: A(0)->buf0, B(0)->buf0, A(1)->buf1, B(1)->buf1 (FIFO order) ----
#pragma unroll
  for (int s = 0; s < 4; ++s) gld16(pA[s], lds + ldsA + (s << 10));
#pragma unroll
  for (int s = 0; s < 4; ++s) gld16(pB[s], lds + ldsB + (s << 10));
#pragma unroll
  for (int s = 0; s < 4; ++s) gld16(pA[s] + 64, lds + 65536 + ldsA + (s << 10));
#pragma unroll
  for (int s = 0; s < 4; ++s) gld16(pB[s] + 64, lds + 65536 + ldsB + (s << 10));
  // in-loop staging at tile j targets k = 64*(j+2):
#pragma unroll
  for (int s = 0; s < 4; ++s) { pA[s] += 128; pB[s] += 128; }
  asm volatile("s_waitcnt vmcnt(8)" ::: "memory");   // A(0),B(0) landed; A(1),B(1) in flight
  BAR;
  RDA(0, 0); RDB(0, 0);    // av0(0), bv01(0) for first M0

  for (int j = 0; j < NT; ++j) {
    const int buf  = (j & 1) << 16;
    const int obuf = buf ^ 65536;
    const bool stA = (j + 1 < NT);       // next-tile reads exist
    const bool stB = (j + 2 < NT);       // tiles j+2 staged
    // p0: M0 [av0,bv01]; read bv23
    MFMAQ(0, 0);
    RDB(buf, 1);
    BAR;
    // p1: M1 [av0,bv23]; read av1 (av regs die at M1 issue)
    MFMAQ(0, 1);
    RDA(buf, 1);
    BAR;
    // p2: stage ALL of B(j+2) -> buf.B (bv01 consumed M0, bv23 consumed M1); M2
    if (stB) {
#pragma unroll
      for (int s = 0; s < 4; ++s) gld16(pB[s], lds + buf + ldsB + (s << 10));
    }
    MFMAQ(1, 1);
    BAR;
    // p3: vmcnt(4) retires A(j+1),B(j+1) (keeps B(j+2)); BAR; stage ALL of
    //     A(j+2) -> buf.A (buf.A reads complete by p2-end BAR); M3; next reads
    if (j < NT - 2)       { asm volatile("s_waitcnt vmcnt(4)" ::: "memory"); }
    else if (j == NT - 2) { asm volatile("s_waitcnt vmcnt(0)" ::: "memory"); }
    BAR;
    if (stB) {
#pragma unroll
      for (int s = 0; s < 4; ++s) gld16(pA[s], lds + buf + ldsA + (s << 10));
    }
    MFMAQ(1, 0);
    if (stA) { RDA(obuf, 0); RDB(obuf, 0); }
#pragma unroll
    for (int s = 0; s < 4; ++s) { pA[s] += 64; pB[s] += 64; }
  }

  // ---- epilogue: C = acc + bias ----
#pragma unroll
  for (int m = 0; m < 8; ++m) {
    const int row0 = brow + wr * 128 + m * 16 + lhi * 4;
#pragma unroll
    for (int n = 0; n < 4; ++n) {
      const int col = bcol + wc * 64 + n * 16 + l15;
      const float b2 = bias[col];
#pragma unroll
      for (int jj = 0; jj < 4; ++jj)
        C[(size_t)(row0 + jj) * ldc + col] = acc[m][n][jj] + b2;
    }
  }
}

// ---------- launch ----------
extern "C" void kernel_launch(void* const* d_in, const int* in_sizes, int n_in,
                              void* d_out, int out_size, void* d_ws, size_t ws_size,
                              hipStream_t stream) {
  const float* x  = (const float*)d_in[0];   // [8192][4096]
  const float* Wb = (const float*)d_in[1];   // [4096][4096]
  const float* bb = (const float*)d_in[2];   // [4096]
  const float* Wg = (const float*)d_in[3];   // [8][4096]
  const float* A  = (const float*)d_in[4];   // [8][16][4096] = [128][4096]
  const float* B  = (const float*)d_in[5];   // [8][4096][16]
  float* out = (float*)d_out;                // [8192][4096]

  char* ws = (char*)d_ws;
  u16*   Xaug = (u16*)ws;                                     // 8192 x 4224 bf16
  u16*   Waug = (u16*)(ws + 69206016);                        // 4096 x 4224 bf16
  u16*   a2   = (u16*)(ws + 69206016 + 34603008);             // 128 x 4096 bf16
  float* wsc  = (float*)(ws + 69206016 + 34603008 + 1048576); // 8192 x 8

  // 1) all input-only work (r15 contiguous mapping — best measured)
  fused_pre<<<3072, 256, 0, stream>>>(x, Wg, Wb, B, A, Xaug, Waug, a2, wsc);

  // 2) lora down-proj + gate-scale
  lora_hw<<<256, 256, 0, stream>>>(Xaug, a2, wsc, Xaug);

  // 3) main fused GEMM: out = Xaug @ Waug^T + bias (A-stage@p3 depth j+2)
  gemm8p<<<512, 512, 0, stream>>>(Xaug, Waug, bb, out, 4224, 4224, 4096, 4224);
}

// Round 20
// 329.680 us; speedup vs baseline: 1.0362x; 1.0362x over previous
//
#include <hip/hip_runtime.h>
#include <stdint.h>

typedef unsigned short u16;
typedef float f32x4 __attribute__((ext_vector_type(4)));
typedef short bf16x8 __attribute__((ext_vector_type(8)));

// ---------- helpers ----------
static __device__ __forceinline__ u16 f2bf(float f) {
  union { float f; unsigned u; } a; a.f = f;
  unsigned r = a.u + 0x7fffu + ((a.u >> 16) & 1u);   // round-nearest-even
  return (u16)(r >> 16);
}

static __device__ __forceinline__ void gld16(const void* g, void* l) {
  __builtin_amdgcn_global_load_lds(
      (const __attribute__((address_space(1))) void*)(uintptr_t)g,
      (__attribute__((address_space(3))) void*)(uintptr_t)l,
      16, 0, 0);
}

// ================== K1: all input-only work (VERBATIM r15 — proven) ==================
__global__ __launch_bounds__(256, 4) void fused_pre(
    const float* __restrict__ x, const float* __restrict__ Wg,
    const float* __restrict__ Wb, const float* __restrict__ B,
    const float* __restrict__ A,
    u16* __restrict__ Xaug, u16* __restrict__ Waug, u16* __restrict__ a2,
    float* __restrict__ wsc) {
  const int bid = blockIdx.x;
  const int t = threadIdx.x;
  if (bid < 512) {
    const int lane = t & 63;
    const int wv = t >> 6;
    const int n0 = bid * 16 + wv * 4;
    const float4* g4 = (const float4*)Wg;      // [8][1024] float4
    float acc[4][8] = {};
#pragma unroll 2
    for (int ii = 0; ii < 16; ++ii) {
      const int i = ii * 64 + lane;
      float4 xv[4];
#pragma unroll
      for (int tok = 0; tok < 4; ++tok) {
        xv[tok] = *(const float4*)(x + (size_t)(n0 + tok) * 4096 + i * 4);
        ushort4 o;
        o.x = f2bf(xv[tok].x); o.y = f2bf(xv[tok].y);
        o.z = f2bf(xv[tok].z); o.w = f2bf(xv[tok].w);
        *(ushort4*)(Xaug + (size_t)(n0 + tok) * 4224 + i * 4) = o;
      }
#pragma unroll
      for (int e = 0; e < 8; ++e) {
        float4 w4 = g4[e * 1024 + i];
#pragma unroll
        for (int tok = 0; tok < 4; ++tok)
          acc[tok][e] += xv[tok].x * w4.x + xv[tok].y * w4.y +
                         xv[tok].z * w4.z + xv[tok].w * w4.w;
      }
    }
#pragma unroll
    for (int tok = 0; tok < 4; ++tok) {
#pragma unroll
      for (int e = 0; e < 8; ++e) {
#pragma unroll
        for (int off = 32; off > 0; off >>= 1)
          acc[tok][e] += __shfl_xor(acc[tok][e], off);
      }
      int i1 = 0; float m1 = acc[tok][0];
#pragma unroll
      for (int e = 1; e < 8; ++e) if (acc[tok][e] > m1) { m1 = acc[tok][e]; i1 = e; }
      int i2 = -1; float m2 = -3.4e38f;
#pragma unroll
      for (int e = 0; e < 8; ++e)
        if (e != i1 && acc[tok][e] > m2) { m2 = acc[tok][e]; i2 = e; }
      float w1 = 1.0f / (1.0f + expf(m2 - m1));   // p1/(p1+p2) softmax+renorm
      float w2 = 1.0f - w1;
      if (lane < 8)
        wsc[(size_t)(n0 + tok) * 8 + lane] =
            (lane == i1) ? w1 : ((lane == i2) ? w2 : 0.0f);
    }
  } else if (bid < 2560) {
    const int total = 4096 * 1056;               // vec4 groups
    for (int v = (bid - 512) * 256 + t; v < total; v += 2048 * 256) {
      const int o = v / 1056;
      const int c = (v - o * 1056) * 4;
      ushort4 out;
      if (c < 4096) {
        float4 w = *(const float4*)(Wb + (size_t)o * 4096 + c);
        out.x = f2bf(w.x); out.y = f2bf(w.y); out.z = f2bf(w.z); out.w = f2bf(w.w);
      } else {
        const int er = c - 4096;
        const int e = er >> 4;
        const int r = er & 15;
        const float* bp = B + ((size_t)e * 4096 + o) * 16 + r;
        out.x = f2bf(bp[0] * 2.0f); out.y = f2bf(bp[1] * 2.0f);
        out.z = f2bf(bp[2] * 2.0f); out.w = f2bf(bp[3] * 2.0f);
      }
      *(ushort4*)(Waug + (size_t)o * 4224 + c) = out;
    }
  } else {
    const int i = (bid - 2560) * 256 + t;        // 0..131071 vec4 groups
    const size_t e = (size_t)i * 4;
    float4 v = *(const float4*)(A + e);
    ushort4 o;
    o.x = f2bf(v.x); o.y = f2bf(v.y); o.z = f2bf(v.z); o.w = f2bf(v.w);
    *(ushort4*)(a2 + e) = o;
  }
}

// ================== K2: LoRA down-proj + gate-scale (VERBATIM r15, proven) ==================
__global__ __launch_bounds__(256) void lora_hw(
    const u16* __restrict__ Xa, const u16* __restrict__ A2,
    const float* __restrict__ wsc, u16* __restrict__ Xaug) {
  __shared__ __align__(1024) char lds[40960];
  const int t = threadIdx.x;
  const int lane = t & 63;
  const int w = t >> 6;
  const int l15 = lane & 15, lhi = lane >> 4;
  const int brow = blockIdx.x * 32;

  const int sb = (lane << 4) ^ (lane & 32);
  const int srow = sb >> 6;
  const int scol = (sb & 63) >> 1;

  const u16* pA = Xa + (size_t)(brow + (w >> 1) * 16 + srow) * 4224 + (w & 1) * 32 + scol;
  const u16* pB[4];
#pragma unroll
  for (int s = 0; s < 4; ++s) {
    const int idx = w * 4 + s;
    pB[s] = A2 + (size_t)((idx >> 1) * 16 + srow) * 4096 + (idx & 1) * 32 + scol;
  }
  const int dA = w << 10;
  const int dB = 4096 + (w << 12);
  const int innerL = ((l15 << 6) + (lhi << 4)) ^ ((l15 & 8) << 2);

  f32x4 acc[2][2] = {};

  gld16(pA, lds + dA);
#pragma unroll
  for (int s = 0; s < 4; ++s) gld16(pB[s], lds + dB + (s << 10));

  for (int j = 0; j < 64; ++j) {
    const int buf = (j & 1) * 20480;
    const int obuf = buf ^ 20480;
    if (j < 63) {
      const int k1 = (j + 1) * 64;
      gld16(pA + k1, lds + obuf + dA);
#pragma unroll
      for (int s = 0; s < 4; ++s) gld16(pB[s] + k1, lds + obuf + dB + (s << 10));
      asm volatile("s_waitcnt vmcnt(5)" ::: "memory");   // tile j landed
    } else {
      asm volatile("s_waitcnt vmcnt(0)" ::: "memory");
    }
    __syncthreads();
    bf16x8 av[2][2], bv[2][2];
#pragma unroll
    for (int m = 0; m < 2; ++m)
#pragma unroll
      for (int kk = 0; kk < 2; ++kk)
        av[m][kk] = *(const bf16x8*)(lds + buf + ((m * 2 + kk) << 10) + innerL);
#pragma unroll
    for (int n = 0; n < 2; ++n)
#pragma unroll
      for (int kk = 0; kk < 2; ++kk)
        bv[n][kk] = *(const bf16x8*)(lds + buf + 4096 + (((w * 2 + n) * 2 + kk) << 10) + innerL);
#pragma unroll
    for (int kk = 0; kk < 2; ++kk)
#pragma unroll
      for (int m = 0; m < 2; ++m)
#pragma unroll
        for (int n = 0; n < 2; ++n)
          acc[m][n] = __builtin_amdgcn_mfma_f32_16x16x32_bf16(av[m][kk], bv[n][kk], acc[m][n], 0, 0, 0);
    __syncthreads();
  }
#pragma unroll
  for (int m = 0; m < 2; ++m) {
    const int rbase = brow + m * 16 + lhi * 4;
#pragma unroll
    for (int n = 0; n < 2; ++n) {
      const int col = w * 32 + n * 16 + l15;
#pragma unroll
      for (int j = 0; j < 4; ++j) {
        const int row = rbase + j;
        const float g = wsc[(size_t)row * 8 + (col >> 4)];
        Xaug[(size_t)row * 4224 + 4096 + col] = f2bf(acc[m][n][j] * g);
      }
    }
  }
}

// ================== 256x256 main GEMM (r18 EXACT — measured best: 232us, MfmaUtil 56) ==================
// r12's 4-barrier pipelined-read schedule with staging repacked: all 4 A(j+1)
// gld16 at p0, all 4 B(j+2) at p2.  vmcnt(4) at p3 retires A(j+1)+B(j+1), keeps
// B(j+2) in flight.  r19's A-stage@p3 variant regressed (48.7 MfmaUtil) ->
// schedule space fully bracketed, this is the optimum of 10 measured variants.
#define BAR do { asm volatile("" ::: "memory"); __builtin_amdgcn_s_barrier(); asm volatile("" ::: "memory"); } while (0)

#define RDA(BUF, MH)                                                            \
  { _Pragma("unroll") for (int mm = 0; mm < 4; ++mm)                            \
    _Pragma("unroll") for (int kk = 0; kk < 2; ++kk)                            \
      av[mm][kk] = *(const bf16x8*)(lds + (BUF) + fbA + ((((MH) * 4 + mm) * 2 + kk) << 10)); }

#define RDB(BUF, NH)                                                            \
  { _Pragma("unroll") for (int nn = 0; nn < 2; ++nn)                            \
    _Pragma("unroll") for (int kk = 0; kk < 2; ++kk)                            \
      bv[(NH) * 2 + nn][kk] = *(const bf16x8*)(lds + (BUF) + fbB + ((((NH) * 2 + nn) * 2 + kk) << 10)); }

#define MFMAQ(MH, NH)                                                           \
  { __builtin_amdgcn_s_setprio(1);                                              \
    _Pragma("unroll") for (int kk = 0; kk < 2; ++kk)                            \
    _Pragma("unroll") for (int mm = 0; mm < 4; ++mm)                            \
    _Pragma("unroll") for (int nn = 0; nn < 2; ++nn)                            \
      acc[(MH) * 4 + mm][(NH) * 2 + nn] = __builtin_amdgcn_mfma_f32_16x16x32_bf16( \
          av[mm][kk], bv[(NH) * 2 + nn][kk], acc[(MH) * 4 + mm][(NH) * 2 + nn], 0, 0, 0); \
    __builtin_amdgcn_s_setprio(0); }

__global__ __launch_bounds__(512, 2) void gemm8p(
    const u16* __restrict__ Ag, const u16* __restrict__ Bg,
    const float* __restrict__ bias, float* __restrict__ C,
    int lda, int ldb, int ldc, int K) {
  __shared__ __align__(1024) char lds[131072];
  const int t = threadIdx.x;
  const int lane = t & 63;
  const int w = t >> 6;
  const int wr = w >> 2, wc = w & 3;
  const int l15 = lane & 15, lhi = lane >> 4;

  // XCD-slab mapping (verified: FETCH 304->203MB)
  const int bid = blockIdx.x;
  const int g = bid >> 3;
  const int tile_m = (bid & 7) * 4 + (g & 3);
  const int tile_n = g >> 2;
  const int brow = tile_m << 8;
  const int bcol = tile_n << 8;

  // pre-swizzled per-lane source coords (st_16x32 involution)
  const int sb = (lane << 4) ^ (lane & 32);
  const int srow = sb >> 6;
  const int scol = (sb & 63) >> 1;

  const u16* pA[4]; const u16* pB[4];
#pragma unroll
  for (int s = 0; s < 4; ++s) {
    const int idx = w * 4 + s;
    const int rg = idx >> 1, cs = idx & 1;
    pA[s] = Ag + (size_t)(brow + rg * 16 + srow) * lda + cs * 32 + scol;
    pB[s] = Bg + (size_t)(bcol + rg * 16 + srow) * ldb + cs * 32 + scol;
  }
  const int ldsA = w << 12;
  const int ldsB = 32768 + (w << 12);

  const int innerL = ((l15 << 6) + (lhi << 4)) ^ ((l15 & 8) << 2);
  const int fbA = (wr << 14) + innerL;
  const int fbB = 32768 + (wc << 13) + innerL;

  f32x4 acc[8][4] = {};
  bf16x8 av[4][2], bv[4][2];

  const int NT = K >> 6;   // 66 K-tiles

#pragma unroll
  for (int s = 0; s < 4; ++s) gld16(pA[s], lds + ldsA + (s << 10));
#pragma unroll
  for (int s = 0; s < 4; ++s) gld16(pB[s], lds + ldsB + (s << 10));
#pragma unroll
  for (int s = 0; s < 4; ++s) gld16(pB[s] + 64, lds + 65536 + ldsB + (s << 10));
#pragma unroll
  for (int s = 0; s < 4; ++s) { pA[s] += 64; pB[s] += 128; }
  asm volatile("s_waitcnt vmcnt(4)" ::: "memory");   // A(0),B(0) landed
  BAR;
  RDA(0, 0); RDB(0, 0);    // av0(0), bv01(0) for first M0

  for (int j = 0; j < NT; ++j) {
    const int buf  = (j & 1) << 16;
    const int obuf = buf ^ 65536;
    const bool stA = (j + 1 < NT);
    const bool stB = (j + 2 < NT);
    // p0: stage ALL of A(j+1); M0 [av0,bv01]; read bv23 (regs free)
    if (stA) {
#pragma unroll
      for (int s = 0; s < 4; ++s) gld16(pA[s], lds + obuf + ldsA + (s << 10));
    }
    MFMAQ(0, 0);
    RDB(buf, 1);
    BAR;
    // p1: M1 [av0,bv23]; read av1 (av regs die at M1 issue)
    MFMAQ(0, 1);
    RDA(buf, 1);
    BAR;
    // p2: stage ALL of B(j+2) -> this buf (bv01 consumed at M0, bv23 at M1); M2
    if (stB) {
#pragma unroll
      for (int s = 0; s < 4; ++s) gld16(pB[s], lds + buf + ldsB + (s << 10));
    }
    MFMAQ(1, 1);
    BAR;
    // p3: vmcnt(4)+BAR (A(j+1),B(j+1) landed; B(j+2)4 stays in flight);
    //     M3 [av1,bv01]; read av0',bv01' from next buf
    if (j < NT - 2)       { asm volatile("s_waitcnt vmcnt(4)" ::: "memory"); }
    else if (j == NT - 2) { asm volatile("s_waitcnt vmcnt(0)" ::: "memory"); }
    BAR;
    MFMAQ(1, 0);
    if (stA) { RDA(obuf, 0); RDB(obuf, 0); }
#pragma unroll
    for (int s = 0; s < 4; ++s) { pA[s] += 64; pB[s] += 64; }
  }

#pragma unroll
  for (int m = 0; m < 8; ++m) {
    const int row0 = brow + wr * 128 + m * 16 + lhi * 4;
#pragma unroll
    for (int n = 0; n < 4; ++n) {
      const int col = bcol + wc * 64 + n * 16 + l15;
      const float b2 = bias[col];
#pragma unroll
      for (int jj = 0; jj < 4; ++jj)
        C[(size_t)(row0 + jj) * ldc + col] = acc[m][n][jj] + b2;
    }
  }
}

// ---------- launch ----------
extern "C" void kernel_launch(void* const* d_in, const int* in_sizes, int n_in,
                              void* d_out, int out_size, void* d_ws, size_t ws_size,
                              hipStream_t stream) {
  const float* x  = (const float*)d_in[0];   // [8192][4096]
  const float* Wb = (const float*)d_in[1];   // [4096][4096]
  const float* bb = (const float*)d_in[2];   // [4096]
  const float* Wg = (const float*)d_in[3];   // [8][4096]
  const float* A  = (const float*)d_in[4];   // [8][16][4096] = [128][4096]
  const float* B  = (const float*)d_in[5];   // [8][4096][16]
  float* out = (float*)d_out;                // [8192][4096]

  char* ws = (char*)d_ws;
  u16*   Xaug = (u16*)ws;                                     // 8192 x 4224 bf16
  u16*   Waug = (u16*)(ws + 69206016);                        // 4096 x 4224 bf16
  u16*   a2   = (u16*)(ws + 69206016 + 34603008);             // 128 x 4096 bf16
  float* wsc  = (float*)(ws + 69206016 + 34603008 + 1048576); // 8192 x 8

  // 1) all input-only work (r15 contiguous mapping — best measured)
  fused_pre<<<3072, 256, 0, stream>>>(x, Wg, Wb, B, A, Xaug, Waug, a2, wsc);

  // 2) lora down-proj + gate-scale
  lora_hw<<<256, 256, 0, stream>>>(Xaug, a2, wsc, Xaug);

  // 3) main fused GEMM: out = Xaug @ Waug^T + bias (r18 schedule — measured best)
  gemm8p<<<512, 512, 0, stream>>>(Xaug, Waug, bb, out, 4224, 4224, 4096, 4224);
}